// Round 9
// baseline (130.499 us; speedup 1.0000x reference)
//
#include <hip/hip_runtime.h>
#include <hip/hip_bf16.h>

// Shapes are fixed by the problem definition.
#define B_   16
#define T_   4096
#define N_   512
#define D_   512
#define EPSF 1e-8f

typedef __attribute__((ext_vector_type(8))) short bf16x8; // 8 bf16 = 4 VGPRs
typedef __attribute__((ext_vector_type(4))) float f32x4;

#define SCHED0 __builtin_amdgcn_sched_barrier(0)

// round-to-nearest-even f32 -> bf16, packed pair into one u32
__device__ __forceinline__ unsigned int pack2bf(float a, float b) {
  unsigned int ua = __float_as_uint(a);
  ua += 0x7fffu + ((ua >> 16) & 1u);
  unsigned int ub = __float_as_uint(b);
  ub += 0x7fffu + ((ub >> 16) & 1u);
  return (ua >> 16) | (ub & 0xffff0000u);
}

// async global->LDS, 16 B per lane
__device__ __forceinline__ void gload_lds16(const void* g, void* l) {
  __builtin_amdgcn_global_load_lds(
      (const __attribute__((address_space(1))) unsigned int*)g,
      (__attribute__((address_space(3))) unsigned int*)l, 16, 0, 0);
}

// ---------------------------------------------------------------------------
// Kernel A: distractor rows -> inv_nd (f32 norms) + bf16 copy (ydbf).
// ---------------------------------------------------------------------------
__global__ void rownorms_d(const float* __restrict__ yd,
                           float* __restrict__ inv_nd,
                           unsigned short* __restrict__ ydbf) {
  const int tid = threadIdx.x;
  const int g   = tid >> 4;
  const int t   = tid & 15;
  const int row = blockIdx.x * 16 + g;
  const float* dr = yd + (size_t)row * D_;
  unsigned short* ob = ydbf + (size_t)row * D_;

  float dd = 0.f;
#pragma unroll
  for (int k = 0; k < 8; ++k) {
    const int col = k * 64 + t * 4;
    float4 a = *(const float4*)(dr + col);
    dd += a.x * a.x + a.y * a.y + a.z * a.z + a.w * a.w;
    uint2 p;
    p.x = pack2bf(a.x, a.y);
    p.y = pack2bf(a.z, a.w);
    *(uint2*)(ob + col) = p;
  }
#pragma unroll
  for (int m = 1; m < 16; m <<= 1) dd += __shfl_xor(dd, m);
  if (t == 0) inv_nd[row] = 1.f / fmaxf(sqrtf(dd), EPSF);
}

// B staging: r6-verbatim addressing (verified, 0 conflicts). 512x64 bf16.
__device__ __forceinline__ void stage_B(unsigned char* buf,
                                        const unsigned short* __restrict__ Bb,
                                        int k0, int tid) {
#pragma unroll
  for (int j = 0; j < 8; ++j) {
    const int g   = j * 512 + tid;          // chunk 0..4095 (16 B each)
    const int row = g >> 3;                 // 8 chunks per 64-bf16 row
    const int sch = (g & 7) ^ (row & 7);    // inverse-swizzled source chunk
    gload_lds16(Bb + (size_t)row * D_ + k0 + (sch << 3), buf + (g << 4));
  }
}

// ---------------------------------------------------------------------------
// Kernel B (r9): 16-phase fine-interleaved pipeline (m201-style T3+T4+T5).
// One block per (mt,b) = 128 rows x N=512, 512 thr / 8 waves (2x4).
// Per iter t (2 phases):
//  Phase A: [issue slot0-loads(t+1); issue stageB(t+1)->Bs[(t+1)&1];
//            ds_read ks0 frags (As[0], Bs[t&1]); writeA(t,ks1)<-slot1 ->As[1];
//            lgkm0; bar; MFMA ks0 x32; bar]
//  Phase B: [issue slot1-loads(t+1); ds_read ks1 frags (As[1], Bs[t&1]);
//            writeA(t+1,ks0)<-slot0 ->As[0];
//            vmcnt(4) lgkm0; bar; MFMA ks1 x32; bar]
// vmcnt(4): outstanding = stageB(t+1)(8, older) + slot1(4, newest) -> waits
// until 4 remain => stageB drained, slot1 still in flight. Never 0 mid-loop.
// As halves ping-pong one phase behind their readers (audited: every write
// lands one-or-more barriers after the buffer's last reader).
// As-half swizzle: chunk = kc ^ (row&3) ^ ((row>>2)&1) -> uniform 2-way
// bank aliasing on read (free, m136). Bs formulas r6-verbatim.
// LDS: 128K Bs + 16K As + 3.5K stats = 147.5K -> 1 block/CU, 8 waves.
// Epilogue fused: per-block log-sum -> atomicAdd(out). No S/rt buffers.
// ---------------------------------------------------------------------------
__launch_bounds__(512, 2)
__global__ void fused_ct(const float* __restrict__ c,
                         const float* __restrict__ yt,
                         const unsigned short* __restrict__ ydbf,
                         const float* __restrict__ inv_nd,
                         float* __restrict__ out) {
  __shared__ __align__(16) unsigned char Bs[2][512 * 64 * 2];  // 2x64 KB
  __shared__ __align__(16) unsigned char As[2][128 * 32 * 2];  // 2x8 KB
  __shared__ float s_invd[512];
  __shared__ float s_invc[128];
  __shared__ float s_rt[128];
  __shared__ float s_S[128];

  // XCD-aware decode: XCD x (= bid%8) gets 64 consecutive original ids
  // = 2 whole batches -> ydbf panel L2-resident per XCD. 512%8==0: bijective.
  const int bid  = blockIdx.x;
  const int orig = (bid & 7) * 64 + (bid >> 3);
  const int b    = orig >> 5;
  const int mt   = orig & 31;

  const int tid  = threadIdx.x;
  const int lane = tid & 63;
  const int w    = tid >> 6;
  const int wm   = w >> 2, wn = w & 3;   // 2 x 4 waves over 128 x 512 out

  const float* Ab = c  + ((size_t)b * T_ + (size_t)mt * 128) * D_;
  const float* Tb = yt + ((size_t)b * T_ + (size_t)mt * 128) * D_;
  const unsigned short* Bb = ydbf + (size_t)b * N_ * D_;

  // A-route geometry: thread owns (row = tid>>2, q = tid&3); per k-half it
  // loads 8 f32 (2 float4) at col khalf*32 + q*8 and writes one b128.
  const int arow = tid >> 2;
  const int q    = tid & 3;
  const int xr   = (arow & 3) ^ ((arow >> 2) & 1);
  unsigned char* As0w = As[0] + (arow << 6) + ((q ^ xr) << 4);
  unsigned char* As1w = As[1] + (arow << 6) + ((q ^ xr) << 4);
  const size_t aoff = (size_t)arow * D_ + q * 8;

  float4 c0a, c0b, t0a, t0b;   // slot0 (ks=0 halves)
  float4 c1a, c1b, t1a, t1b;   // slot1 (ks=1 halves)
  float cc = 0.f, ttv = 0.f, ctv = 0.f;

  // ---- prologue ----
  stage_B(Bs[0], Bb, 0, tid);                               // 8 gloads
  { const float* p = Ab + aoff;       c0a = *(const float4*)p; c0b = *(const float4*)(p + 4);
    const float* y = Tb + aoff;       t0a = *(const float4*)y; t0b = *(const float4*)(y + 4); }
  { const float* p = Ab + aoff + 32;  c1a = *(const float4*)p; c1b = *(const float4*)(p + 4);
    const float* y = Tb + aoff + 32;  t1a = *(const float4*)y; t1b = *(const float4*)(y + 4); }
  s_invd[tid] = inv_nd[b * N_ + tid];
  if (tid < 128) s_S[tid] = 0.f;
  { // writeA(0, ks0) -> As[0]; consuming slot0 drains stage_B(0) (older).
    uint4 v;
    v.x = pack2bf(c0a.x, c0a.y); v.y = pack2bf(c0a.z, c0a.w);
    v.z = pack2bf(c0b.x, c0b.y); v.w = pack2bf(c0b.z, c0b.w);
    *(uint4*)As0w = v;
    cc  += c0a.x*c0a.x + c0a.y*c0a.y + c0a.z*c0a.z + c0a.w*c0a.w
         + c0b.x*c0b.x + c0b.y*c0b.y + c0b.z*c0b.z + c0b.w*c0b.w;
    ttv += t0a.x*t0a.x + t0a.y*t0a.y + t0a.z*t0a.z + t0a.w*t0a.w
         + t0b.x*t0b.x + t0b.y*t0b.y + t0b.z*t0b.z + t0b.w*t0b.w;
    ctv += c0a.x*t0a.x + c0a.y*t0a.y + c0a.z*t0a.z + c0a.w*t0a.w
         + c0b.x*t0b.x + c0b.y*t0b.y + c0b.z*t0b.z + c0b.w*t0b.w;
  }
  SCHED0; asm volatile("s_waitcnt lgkmcnt(0)" ::: "memory"); SCHED0;
  __builtin_amdgcn_s_barrier(); SCHED0;

  f32x4 acc[4][8] = {};
  const int kc = lane >> 4;

#pragma unroll 1
  for (int t = 0; t < 8; ++t) {
    const unsigned char* Bcur = Bs[t & 1];
    unsigned char* Bnxt = Bs[(t + 1) & 1];

    // ================= PHASE A (ks = 0) =================
    if (t < 7) {
      const float* p = Ab + aoff + (t + 1) * 64;
      const float* y = Tb + aoff + (t + 1) * 64;
      c0a = *(const float4*)p; c0b = *(const float4*)(p + 4);
      t0a = *(const float4*)y; t0b = *(const float4*)(y + 4);
      stage_B(Bnxt, Bb, (t + 1) * 64, tid);
    }
    bf16x8 af[4], bfr[8];
#pragma unroll
    for (int i = 0; i < 4; ++i) {
      const int ar = wm * 64 + i * 16 + (lane & 15);
      const int xa = (ar & 3) ^ ((ar >> 2) & 1);
      af[i] = *(const bf16x8*)(As[0] + (ar << 6) + ((kc ^ xa) << 4));
    }
#pragma unroll
    for (int n = 0; n < 8; ++n) {
      const int br = wn * 128 + n * 16 + (lane & 15);
      bfr[n] = *(const bf16x8*)(Bcur + (br << 7) + ((kc ^ (br & 7)) << 4));
    }
    { // writeA(t, ks1) <- slot1 -> As[1]
      uint4 v;
      v.x = pack2bf(c1a.x, c1a.y); v.y = pack2bf(c1a.z, c1a.w);
      v.z = pack2bf(c1b.x, c1b.y); v.w = pack2bf(c1b.z, c1b.w);
      *(uint4*)As1w = v;
      cc  += c1a.x*c1a.x + c1a.y*c1a.y + c1a.z*c1a.z + c1a.w*c1a.w
           + c1b.x*c1b.x + c1b.y*c1b.y + c1b.z*c1b.z + c1b.w*c1b.w;
      ttv += t1a.x*t1a.x + t1a.y*t1a.y + t1a.z*t1a.z + t1a.w*t1a.w
           + t1b.x*t1b.x + t1b.y*t1b.y + t1b.z*t1b.z + t1b.w*t1b.w;
      ctv += c1a.x*t1a.x + c1a.y*t1a.y + c1a.z*t1a.z + c1a.w*t1a.w
           + c1b.x*t1b.x + c1b.y*t1b.y + c1b.z*t1b.z + c1b.w*t1b.w;
    }
    SCHED0; asm volatile("s_waitcnt lgkmcnt(0)" ::: "memory"); SCHED0;
    __builtin_amdgcn_s_barrier(); SCHED0;
    __builtin_amdgcn_s_setprio(1);
#pragma unroll
    for (int mi = 0; mi < 4; ++mi)
#pragma unroll
      for (int ni = 0; ni < 8; ++ni)
        acc[mi][ni] = __builtin_amdgcn_mfma_f32_16x16x32_bf16(
            af[mi], bfr[ni], acc[mi][ni], 0, 0, 0);
    __builtin_amdgcn_s_setprio(0);
    SCHED0; __builtin_amdgcn_s_barrier(); SCHED0;

    // ================= PHASE B (ks = 1) =================
    if (t < 7) {
      const float* p = Ab + aoff + (t + 1) * 64 + 32;
      const float* y = Tb + aoff + (t + 1) * 64 + 32;
      c1a = *(const float4*)p; c1b = *(const float4*)(p + 4);
      t1a = *(const float4*)y; t1b = *(const float4*)(y + 4);
    }
#pragma unroll
    for (int i = 0; i < 4; ++i) {
      const int ar = wm * 64 + i * 16 + (lane & 15);
      const int xa = (ar & 3) ^ ((ar >> 2) & 1);
      af[i] = *(const bf16x8*)(As[1] + (ar << 6) + ((kc ^ xa) << 4));
    }
#pragma unroll
    for (int n = 0; n < 8; ++n) {
      const int br = wn * 128 + n * 16 + (lane & 15);
      bfr[n] = *(const bf16x8*)(Bcur + (br << 7) + (((4 + kc) ^ (br & 7)) << 4));
    }
    if (t < 7) { // writeA(t+1, ks0) <- slot0 -> As[0]
      uint4 v;
      v.x = pack2bf(c0a.x, c0a.y); v.y = pack2bf(c0a.z, c0a.w);
      v.z = pack2bf(c0b.x, c0b.y); v.w = pack2bf(c0b.z, c0b.w);
      *(uint4*)As0w = v;
      cc  += c0a.x*c0a.x + c0a.y*c0a.y + c0a.z*c0a.z + c0a.w*c0a.w
           + c0b.x*c0b.x + c0b.y*c0b.y + c0b.z*c0b.z + c0b.w*c0b.w;
      ttv += t0a.x*t0a.x + t0a.y*t0a.y + t0a.z*t0a.z + t0a.w*t0a.w
           + t0b.x*t0b.x + t0b.y*t0b.y + t0b.z*t0b.z + t0b.w*t0b.w;
      ctv += c0a.x*t0a.x + c0a.y*t0a.y + c0a.z*t0a.z + c0a.w*t0a.w
           + c0b.x*t0b.x + c0b.y*t0b.y + c0b.z*t0b.z + c0b.w*t0b.w;
    }
    SCHED0;
    if (t < 7) asm volatile("s_waitcnt vmcnt(4) lgkmcnt(0)" ::: "memory");
    else       asm volatile("s_waitcnt vmcnt(0) lgkmcnt(0)" ::: "memory");
    SCHED0;
    __builtin_amdgcn_s_barrier(); SCHED0;
    __builtin_amdgcn_s_setprio(1);
#pragma unroll
    for (int mi = 0; mi < 4; ++mi)
#pragma unroll
      for (int ni = 0; ni < 8; ++ni)
        acc[mi][ni] = __builtin_amdgcn_mfma_f32_16x16x32_bf16(
            af[mi], bfr[ni], acc[mi][ni], 0, 0, 0);
    __builtin_amdgcn_s_setprio(0);
    SCHED0; __builtin_amdgcn_s_barrier(); SCHED0;
  }

  // ---- stats: reduce over q (4 consecutive lanes share a row) ----
  cc  += __shfl_xor(cc, 1);  cc  += __shfl_xor(cc, 2);
  ttv += __shfl_xor(ttv, 1); ttv += __shfl_xor(ttv, 2);
  ctv += __shfl_xor(ctv, 1); ctv += __shfl_xor(ctv, 2);
  if (q == 0) {
    const float nc = fmaxf(sqrtf(cc), EPSF);
    const float nt = fmaxf(sqrtf(ttv), EPSF);
    s_invc[arow] = 1.f / nc;
    s_rt[arow]   = ctv / (nt * nc);
  }
  __syncthreads();

  // ---- epilogue: exp row-sums into s_S (LDS atomics) ----
  float invd[8];
#pragma unroll
  for (int ni = 0; ni < 8; ++ni)
    invd[ni] = s_invd[wn * 128 + ni * 16 + (lane & 15)];

#pragma unroll
  for (int mi = 0; mi < 4; ++mi) {
    const int t0l = wm * 64 + mi * 16 + ((lane >> 4) << 2);
#pragma unroll
    for (int r = 0; r < 4; ++r) {
      const float invc = s_invc[t0l + r];
      float s = 0.f;
#pragma unroll
      for (int ni = 0; ni < 8; ++ni)
        s += __expf(acc[mi][ni][r] * invc * invd[ni]);
      s += __shfl_xor(s, 1);
      s += __shfl_xor(s, 2);
      s += __shfl_xor(s, 4);
      s += __shfl_xor(s, 8);
      if ((lane & 15) == 0) atomicAdd(&s_S[t0l + r], s);
    }
  }
  __syncthreads();

  // ---- final: block-local log-sum -> one atomicAdd per wave-of-2 ----
  if (tid < 128) {
    const float r = s_rt[tid];
    float term = logf(s_S[tid] + __expf(r)) - r;
#pragma unroll
    for (int m = 1; m < 64; m <<= 1) term += __shfl_xor(term, m);
    if ((tid & 63) == 0) atomicAdd(out, term);
  }
}

// ---------------------------------------------------------------------------
extern "C" void kernel_launch(void* const* d_in, const int* in_sizes, int n_in,
                              void* d_out, int out_size, void* d_ws, size_t ws_size,
                              hipStream_t stream) {
  (void)in_sizes; (void)n_in; (void)out_size; (void)ws_size;
  const float* c  = (const float*)d_in[0];
  const float* yt = (const float*)d_in[1];
  const float* yd = (const float*)d_in[2];
  float* out = (float*)d_out;

  // ws layout: [ydbf: B*N*D u16][inv_nd: B*N f]
  const size_t ydbf_n = (size_t)B_ * N_ * D_;   // 4.2M u16 = 8 MiB
  unsigned short* ydbf = (unsigned short*)d_ws;
  float* inv_nd = (float*)(ydbf + ydbf_n);      // B*N

  hipMemsetAsync(out, 0, sizeof(float), stream);

  rownorms_d<<<B_ * N_ / 16, 256, 0, stream>>>(yd, inv_nd, ydbf);

  fused_ct<<<512, 512, 0, stream>>>(c, yt, ydbf, inv_nd, out);
}